// Round 14
// baseline (260.407 us; speedup 1.0000x reference)
//
#include <hip/hip_runtime.h>

#define TSTEPS 15
#define HID    64
#define LAT    16
#define NBATCH 65536
#define LOG2E  1.44269504088896f

typedef _Float16 v8h __attribute__((ext_vector_type(8)));
typedef _Float16 v4h __attribute__((ext_vector_type(4)));
typedef _Float16 v2h __attribute__((ext_vector_type(2)));
typedef float    v4f __attribute__((ext_vector_type(4)));
typedef float    v2f __attribute__((ext_vector_type(2)));

__device__ __forceinline__ v8h vzero8() {
    v8h v;
#pragma unroll
    for (int i = 0; i < 8; ++i) v[i] = (_Float16)0.0f;
    return v;
}

// v_cvt_pkrtz returns __fp16x2; bit-cast to our _Float16x2 (same bits).
__device__ __forceinline__ v4h pack4(float a, float b, float c, float d) {
    const v2h lo = __builtin_bit_cast(v2h, __builtin_amdgcn_cvt_pkrtz(a, b));
    const v2h hi = __builtin_bit_cast(v2h, __builtin_amdgcn_cvt_pkrtz(c, d));
    return __builtin_shufflevector(lo, hi, 0, 1, 2, 3);
}

__device__ __forceinline__ v2f exp2_2(v2f x) {
    v2f r; r.x = __builtin_amdgcn_exp2f(x.x); r.y = __builtin_amdgcn_exp2f(x.y);
    return r;
}
__device__ __forceinline__ v2f rcp_2(v2f x) {
    v2f r; r.x = __builtin_amdgcn_rcpf(x.x); r.y = __builtin_amdgcn_rcpf(x.y);
    return r;
}

// LSTM cell update, 2 units at a time (v2f -> v_pk_*_f32 full-rate packed).
// Gate pre-acts arrive PRE-SCALED by log2e (folded into staged weights).
//   sig(a)*tanh(b) = (1-e2)*rcp((1+e1)(1+e2)),  e1=exp2(-a'), e2=exp2(-2b')
// Trans ops stay scalar (no packed exp2/rcp on CDNA4): 5 exp2 + 3 rcp per
// unit; the surrounding adds/muls/fmas pack 2-wide.
__device__ __forceinline__ v2f cell_update2(v2f ai, v2f af, v2f ag, v2f ao,
                                            v2f& cst) {
    const v2f one = {1.0f, 1.0f};
    const v2f ei = exp2_2(-ai);
    const v2f ef = exp2_2(-af);
    const v2f eg = exp2_2(-2.0f * ag);
    const v2f eo = exp2_2(-ao);
    const v2f ig = (one - eg) * rcp_2((one + ei) * (one + eg));   // i*g
    const v2f f  = rcp_2(one + ef);                               // forget
    const v2f cc = f * cst + ig;                                  // v_pk_fma
    cst = cc;
    const v2f ec = exp2_2(cc * (-2.0f * LOG2E));                  // true scale
    return (one - ec) * rcp_2((one + eo) * (one + ec));           // o*tanh(c)
}

// Software-pipelined fused 2-layer LSTM + FC.
// 16 waves/block (1024 thr) x N=16 batch/wave -> 4 waves/SIMD (the cap:
// 112 KB weight residency forces 1 block/CU; fp8 weights would fit 2
// blocks but e4m3's ~6% weight quantization breaks the error budget).
// At this occupancy the 128-reg unified budget splits 64 VGPR + 64 AGPR
// (VGPR_Count=64 is benign here -- NOT the r3/r4 spill storm; tripwire is
// WRITE_SIZE ~5.9 MB / FETCH ~3.5 MB).
//
// LOAD-BEARING (round 7): without the per-iteration asm memory clobber,
// LICM hoists all A-fragment ds_reads (448 VGPRs worth) out of the t-loop
// -> forced scratch spill -> 3-4 GB HBM scratch traffic. DO NOT REMOVE.
// (Pre-loop register loads are SSA values and survive the clobber.)
//
// Round 14: (a) cohort phase-split -- odd waves run the body as
// L1(t-1)->L0(t), even waves as L0(t)->L1(t-1), anti-aligning trans/MFMA
// bursts across co-resident waves on a SIMD (both orders respect the LDS
// state machine; l1_part is register-only); (b) v2f packed epilogue.
//
//   D[m=gate(256), n=batch(16)] = A[weights*log2e] * B[z | h0 | x | h1]
// wf planes: 0=Wih0(z,K16; k=16 -> bias; rest 0) 1,2=Whh0 3,4=Wih1 5,6=Whh1.
// Gate order (PyTorch): 0=i,1=f,2=g,3=o ; g = 64*type + u, u=16a+4q+r;
// acc[ty] -> ty IS the gate type (mt = 4*ty+a).
__global__ __launch_bounds__(1024)
__attribute__((amdgpu_waves_per_eu(4, 4)))
void lstm2_pipe5(
        const float* __restrict__ z,
        const float* __restrict__ Wih0, const float* __restrict__ Whh0,
        const float* __restrict__ bih0, const float* __restrict__ bhh0,
        const float* __restrict__ Wih1, const float* __restrict__ Whh1,
        const float* __restrict__ bih1, const float* __restrict__ bhh1,
        const float* __restrict__ Wfc,  const float* __restrict__ bfc,
        float* __restrict__ out)
{
    __shared__ __align__(16) _Float16 wf[7 * 16 * 64 * 8];   // 114688 B
    __shared__ __align__(16) _Float16 wfcf[2 * 64 * 8];      //   2048 B
    __shared__ __align__(16) float    bsum1[256];            //   1024 B
    __shared__ __align__(16) _Float16 state[16][16 * 72];    //  36864 B
                                                             // 154624 B total

    const int tid  = threadIdx.x;
    const int wave = tid >> 6;           // 0..15
    const int lane = tid & 63;
    const int q    = lane >> 4;          // quad
    const int c    = lane & 15;          // batch col
    const int row0 = blockIdx.x * 256 + wave * 16;   // wave's batch base

    /* ------- one-time staging: weights + biases, all scaled by log2e ----- */
#pragma unroll 2
    for (int e = tid; e < 7 * 16 * 64 * 8; e += 1024) {
        const int j  = e & 7;
        const int lm = (e >> 3) & 63;
        const int mt = (e >> 9) & 15;
        const int p  = e >> 13;                  // fragment plane 0..6
        const int g  = mt * 16 + (lm & 15);      // gate row 0..255
        const int kk = (lm >> 4) * 8 + j;        // k within 32-chunk
        float v;
        if (p == 0)      v = (kk < LAT) ? Wih0[g * LAT + kk]
                           : (kk == LAT ? bih0[g] + bhh0[g] : 0.0f);
        else if (p == 1) v = Whh0[g * HID + kk];
        else if (p == 2) v = Whh0[g * HID + 32 + kk];
        else if (p == 3) v = Wih1[g * HID + kk];
        else if (p == 4) v = Wih1[g * HID + 32 + kk];
        else if (p == 5) v = Whh1[g * HID + kk];
        else             v = Whh1[g * HID + 32 + kk];
        wf[e] = (_Float16)(v * LOG2E);
    }
    // FC A-fragments: row m=0 carries Wfc (TRUE scale), rows 1..15 zero
    if (tid < 2 * 64 * 8) {
        const int e  = tid;
        const int j  = e & 7;
        const int lm = (e >> 3) & 63;
        const int kc = e >> 9;
        const int kk = kc * 32 + (lm >> 4) * 8 + j;
        wfcf[e] = ((lm & 15) == 0) ? (_Float16)Wfc[kk] : (_Float16)0.0f;
    }
    if (tid < 256) bsum1[tid] = (bih1[tid] + bhh1[tid]) * LOG2E;
    __syncthreads();   // the only barrier in the kernel

    _Float16* stW = &state[wave][0];
    const float bfcv = bfc[0];

    // FC fragments hoisted (SSA regs survive the clobber)
    const v8h wfc0 = *(const v8h*)&wfcf[(0 * 64 + lane) * 8];
    const v8h wfc1 = *(const v8h*)&wfcf[(1 * 64 + lane) * 8];

    // z B-fragment (constant over t); element k=16 = 1.0 multiplies the
    // (log2e-scaled) bias column staged in plane 0.
    v8h zfrag = vzero8();
    if (q < 2) {
        const float* zp = z + (size_t)(row0 + c) * LAT + q * 8;
        const float4 za = *(const float4*)(zp);
        const float4 zb = *(const float4*)(zp + 4);
        zfrag[0] = (_Float16)za.x; zfrag[1] = (_Float16)za.y;
        zfrag[2] = (_Float16)za.z; zfrag[3] = (_Float16)za.w;
        zfrag[4] = (_Float16)zb.x; zfrag[5] = (_Float16)zb.y;
        zfrag[6] = (_Float16)zb.z; zfrag[7] = (_Float16)zb.w;
    }
    if (q == 2) zfrag[0] = (_Float16)1.0f;   // bias slot

    v8h hf0 = vzero8(), hf1 = vzero8();   // h0/x B-frags (k-halves)
    v8h gf0 = vzero8(), gf1 = vzero8();   // h1 B-frags
    v4h h1pk[4];                          // packed h1 awaiting deferred write
    v2f c0s[8], c1s[8];                   // c-state as r-pairs
#pragma unroll
    for (int i = 0; i < 8; ++i) { c0s[i] = (v2f){0.f, 0.f}; c1s[i] = (v2f){0.f, 0.f}; }

#define AFRAG(pl, mt) (*(const v8h*)&wf[(((pl) * 16 + (mt)) * 64 + lane) * 8])
#define MFMA16(A, B, C) __builtin_amdgcn_mfma_f32_16x16x32_f16((A), (B), (C), 0, 0, 0)

    auto l0_part = [&]() {   // L0 MFMAs + epilogue + h0 stores (uses old hf)
#pragma unroll
        for (int a = 0; a < 4; ++a) {
            v4f acc0[4];
#pragma unroll
            for (int ty = 0; ty < 4; ++ty) {
                const int mt = 4 * ty + a;
                v4f t0 = {0.f, 0.f, 0.f, 0.f};
                t0 = MFMA16(AFRAG(0, mt), zfrag, t0);
                t0 = MFMA16(AFRAG(1, mt), hf0,   t0);
                t0 = MFMA16(AFRAG(2, mt), hf1,   t0);
                acc0[ty] = t0;
            }
            const v2f h01 = cell_update2(
                (v2f){acc0[0][0], acc0[0][1]}, (v2f){acc0[1][0], acc0[1][1]},
                (v2f){acc0[2][0], acc0[2][1]}, (v2f){acc0[3][0], acc0[3][1]},
                c0s[a * 2]);
            const v2f h23 = cell_update2(
                (v2f){acc0[0][2], acc0[0][3]}, (v2f){acc0[1][2], acc0[1][3]},
                (v2f){acc0[2][2], acc0[2][3]}, (v2f){acc0[3][2], acc0[3][3]},
                c0s[a * 2 + 1]);
            *(v4h*)&stW[c * 72 + 16 * a + 4 * q] = pack4(h01.x, h01.y, h23.x, h23.y);
        }
    };

    auto l1_part = [&]() {   // L1 MFMAs + epilogue -> h1pk (uses old hf, gf)
#pragma unroll
        for (int a = 0; a < 4; ++a) {
            v4f acc1[4];
#pragma unroll
            for (int ty = 0; ty < 4; ++ty) {
                const int mt = 4 * ty + a;
                v4f t0 = *(const v4f*)&bsum1[64 * ty + 16 * a + 4 * q];
                t0 = MFMA16(AFRAG(3, mt), hf0, t0);
                t0 = MFMA16(AFRAG(4, mt), hf1, t0);
                t0 = MFMA16(AFRAG(5, mt), gf0, t0);
                t0 = MFMA16(AFRAG(6, mt), gf1, t0);
                acc1[ty] = t0;
            }
            const v2f h01 = cell_update2(
                (v2f){acc1[0][0], acc1[0][1]}, (v2f){acc1[1][0], acc1[1][1]},
                (v2f){acc1[2][0], acc1[2][1]}, (v2f){acc1[3][0], acc1[3][1]},
                c1s[a * 2]);
            const v2f h23 = cell_update2(
                (v2f){acc1[0][2], acc1[0][3]}, (v2f){acc1[1][2], acc1[1][3]},
                (v2f){acc1[2][2], acc1[2][3]}, (v2f){acc1[3][2], acc1[3][3]},
                c1s[a * 2 + 1]);
            h1pk[a] = pack4(h01.x, h01.y, h23.x, h23.y);
        }
    };

    auto l0_finish = [&]() {   // pull new h0 into B-frag registers
        hf0 = *(const v8h*)&stW[c * 72 + 8 * q];
        hf1 = *(const v8h*)&stW[c * 72 + 32 + 8 * q];
    };

    auto l1_finish = [&](int trow) {   // h1 store, gf reload, FC, out
#pragma unroll
        for (int a = 0; a < 4; ++a)
            *(v4h*)&stW[c * 72 + 16 * a + 4 * q] = h1pk[a];
        gf0 = *(const v8h*)&stW[c * 72 + 8 * q];
        gf1 = *(const v8h*)&stW[c * 72 + 32 + 8 * q];
        v4f f = {0.f, 0.f, 0.f, 0.f};
        f = MFMA16(wfc0, gf0, f);
        f = MFMA16(wfc1, gf1, f);
        if (lane < 16)
            out[(size_t)(row0 + lane) * TSTEPS + trow] = f[0] + bfcv;
    };

    /* --------------------------- pipeline --------------------------- */
    l0_part();          // L0 step 0 (hf, gf are zero)
    l0_finish();

    const bool odd = (wave & 1) != 0;   // cohort phase-split (wave-uniform)

#pragma unroll 1
    for (int tt = 1; tt < TSTEPS; ++tt) {
        // Kill LICM (see header comment). Emits no instructions.
        __asm__ __volatile__("" ::: "memory");
        if (odd) {
            l1_part();           // -> h1pk (registers only; uses old hf/gf)
            l0_part();           // writes h0(tt) to stW
        } else {
            l0_part();
            l1_part();
        }
        l0_finish();         // hf <- h0(tt)
        l1_finish(tt - 1);   // h1 store, gf <- h1(tt-1), FC, out row tt-1
    }

    __asm__ __volatile__("" ::: "memory");
    l1_part();          // L1 step 14
    l1_finish(TSTEPS - 1);

#undef AFRAG
#undef MFMA16
}

extern "C" void kernel_launch(void* const* d_in, const int* in_sizes, int n_in,
                              void* d_out, int out_size, void* d_ws, size_t ws_size,
                              hipStream_t stream)
{
    (void)in_sizes; (void)n_in; (void)out_size; (void)d_ws; (void)ws_size;

    const float* z    = (const float*)d_in[0];
    const float* Wih0 = (const float*)d_in[1];
    const float* Whh0 = (const float*)d_in[2];
    const float* bih0 = (const float*)d_in[3];
    const float* bhh0 = (const float*)d_in[4];
    const float* Wih1 = (const float*)d_in[5];
    const float* Whh1 = (const float*)d_in[6];
    const float* bih1 = (const float*)d_in[7];
    const float* bhh1 = (const float*)d_in[8];
    const float* Wfc  = (const float*)d_in[9];
    const float* bfc  = (const float*)d_in[10];

    lstm2_pipe5<<<dim3(NBATCH / 256), dim3(1024), 0, stream>>>(
        z, Wih0, Whh0, bih0, bhh0, Wih1, Whh1, bih1, bhh1, Wfc, bfc,
        (float*)d_out);
}

// Round 15
// 254.777 us; speedup vs baseline: 1.0221x; 1.0221x over previous
//
#include <hip/hip_runtime.h>

#define TSTEPS 15
#define HID    64
#define LAT    16
#define NBATCH 65536
#define LOG2E  1.44269504088896f

typedef _Float16 v8h __attribute__((ext_vector_type(8)));
typedef _Float16 v4h __attribute__((ext_vector_type(4)));
typedef _Float16 v2h __attribute__((ext_vector_type(2)));
typedef float    v4f __attribute__((ext_vector_type(4)));
typedef float    v2f __attribute__((ext_vector_type(2)));

__device__ __forceinline__ v8h vzero8() {
    v8h v;
#pragma unroll
    for (int i = 0; i < 8; ++i) v[i] = (_Float16)0.0f;
    return v;
}

__device__ __forceinline__ v4h pack4(float a, float b, float c, float d) {
    const v2h lo = __builtin_bit_cast(v2h, __builtin_amdgcn_cvt_pkrtz(a, b));
    const v2h hi = __builtin_bit_cast(v2h, __builtin_amdgcn_cvt_pkrtz(c, d));
    return __builtin_shufflevector(lo, hi, 0, 1, 2, 3);
}

__device__ __forceinline__ v2f exp2_2(v2f x) {
    v2f r; r.x = __builtin_amdgcn_exp2f(x.x); r.y = __builtin_amdgcn_exp2f(x.y);
    return r;
}
__device__ __forceinline__ v2f rcp_2(v2f x) {
    v2f r; r.x = __builtin_amdgcn_rcpf(x.x); r.y = __builtin_amdgcn_rcpf(x.y);
    return r;
}

// LSTM cell update, 2 units (v2f packed full-rate ops; trans stays scalar).
// Pre-acts arrive PRE-SCALED by log2e (folded into staged weights/biases).
//   sig(a)*tanh(b) = (1-e2)*rcp((1+e1)(1+e2))
__device__ __forceinline__ v2f cell_update2(v2f ai, v2f af, v2f ag, v2f ao,
                                            v2f& cst) {
    const v2f one = {1.0f, 1.0f};
    const v2f ei = exp2_2(-ai);
    const v2f ef = exp2_2(-af);
    const v2f eg = exp2_2(-2.0f * ag);
    const v2f eo = exp2_2(-ao);
    const v2f ig = (one - eg) * rcp_2((one + ei) * (one + eg));   // i*g
    const v2f f  = rcp_2(one + ef);                               // forget
    const v2f cc = f * cst + ig;
    cst = cc;
    const v2f ec = exp2_2(cc * (-2.0f * LOG2E));                  // true scale
    return (one - ec) * rcp_2((one + eo) * (one + ec));           // o*tanh(c)
}

// Fused 2-layer LSTM + FC. Round 15: N=32 batch/wave, 8 waves (2/SIMD),
// 256-reg budget (waves_per_eu(2,2)), and the t-invariant z-projection
// (Wih0*z + b0, log2e-scaled) hoisted OUT of the t-loop into 128
// accumulator-side registers (computed once by MFMA from a plane staged
// temporarily in the state-buffer overlay). Effects vs r13/14:
//   A-frag ds_reads: 224 -> 96 per wave-step per 32 batch (-57% LDS traffic)
//   MFMA: -14%; plane 0 leaves LDS (wf = 6 planes, total LDS 138 KB).
//
// LOAD-BEARING (round 7): without the per-iteration asm memory clobber,
// LICM hoists all A-fragment ds_reads out of the t-loop -> forced scratch
// spill -> GBs of HBM scratch traffic. DO NOT REMOVE. (Pre-loop register
// values -- zproj, wfc, zfrag -- are SSA and survive the clobber.)
//
// Body ordering (per wave; same-wave LDS ops are ordered, no barriers):
//   l1_part: MFMA(hf=h0(t-1), gf=h1(t-2)) -> epilogue -> write h1(t-1)
//   l1_finish: gf <- h1(t-1), FC MFMA, out(t-1)
//   l0_part: MFMA(zproj, hf) -> epilogue -> write h0(t)
//   l0_finish: hf <- h0(t)
// stW content is always dead when overwritten (read into regs just after
// each write).
//
//   D[m=gate(256), n=batch(32)] = A[weights*log2e] * B[h0 | x | h1]
// wf planes: 0,1=Whh0  2,3=Wih1  4,5=Whh1 (k-halves).
// Gate order (PyTorch): 0=i,1=f,2=g,3=o ; g = 64*type + u, u=16a+4q+r;
// acc[n][ty] -> ty IS the gate type (mt = 4*ty+a).
__global__ __launch_bounds__(512)
__attribute__((amdgpu_waves_per_eu(2, 2)))
void lstm2_zp(
        const float* __restrict__ z,
        const float* __restrict__ Wih0, const float* __restrict__ Whh0,
        const float* __restrict__ bih0, const float* __restrict__ bhh0,
        const float* __restrict__ Wih1, const float* __restrict__ Whh1,
        const float* __restrict__ bih1, const float* __restrict__ bhh1,
        const float* __restrict__ Wfc,  const float* __restrict__ bfc,
        float* __restrict__ out)
{
    __shared__ __align__(16) _Float16 wf[6 * 16 * 64 * 8];   //  98304 B
    __shared__ __align__(16) _Float16 wfcf[2 * 64 * 8];      //   2048 B
    __shared__ __align__(16) float    bsum1[256];            //   1024 B
    __shared__ __align__(16) _Float16 state[8][32 * 72];     //  36864 B
                                                             // 138240 B total

    const int tid  = threadIdx.x;
    const int wave = tid >> 6;           // 0..7
    const int lane = tid & 63;
    const int q    = lane >> 4;          // quad
    const int c    = lane & 15;          // batch col within group
    const int row0 = blockIdx.x * 256 + wave * 32;   // wave's batch base

    /* ------- one-time staging: 6 weight planes (x log2e) ----------------- */
#pragma unroll 4
    for (int e = tid; e < 6 * 16 * 64 * 8; e += 512) {
        const int j  = e & 7;
        const int lm = (e >> 3) & 63;
        const int mt = (e >> 9) & 15;
        const int p  = e >> 13;                  // plane 0..5
        const int g  = mt * 16 + (lm & 15);      // gate row 0..255
        const int kk = (lm >> 4) * 8 + j;        // k within 32-chunk
        float v;
        if (p == 0)      v = Whh0[g * HID + kk];
        else if (p == 1) v = Whh0[g * HID + 32 + kk];
        else if (p == 2) v = Wih1[g * HID + kk];
        else if (p == 3) v = Wih1[g * HID + 32 + kk];
        else if (p == 4) v = Whh1[g * HID + kk];
        else             v = Whh1[g * HID + 32 + kk];
        wf[e] = (_Float16)(v * LOG2E);
    }
    // z-projection plane (Wih0 K=16 + bias col at k=16, x log2e), staged
    // TEMPORARILY in the state-buffer overlay; consumed once below.
    _Float16* zw = &state[0][0];         // 16 KB <= 36864 B overlay
#pragma unroll 4
    for (int e = tid; e < 16 * 64 * 8; e += 512) {
        const int j  = e & 7;
        const int lm = (e >> 3) & 63;
        const int mt = e >> 9;
        const int g  = mt * 16 + (lm & 15);
        const int kk = (lm >> 4) * 8 + j;
        float v = 0.0f;
        if (kk < LAT)       v = Wih0[g * LAT + kk];
        else if (kk == LAT) v = bih0[g] + bhh0[g];
        zw[e] = (_Float16)(v * LOG2E);
    }
    // FC A-fragments: row m=0 carries Wfc (TRUE scale), rows 1..15 zero
#pragma unroll
    for (int e = tid; e < 2 * 64 * 8; e += 512) {
        const int j  = e & 7;
        const int lm = (e >> 3) & 63;
        const int kc = e >> 9;
        const int kk = kc * 32 + (lm >> 4) * 8 + j;
        wfcf[e] = ((lm & 15) == 0) ? (_Float16)Wfc[kk] : (_Float16)0.0f;
    }
    if (tid < 256) bsum1[tid] = (bih1[tid] + bhh1[tid]) * LOG2E;
    __syncthreads();

    _Float16* stW = &state[wave][0];
    const float bfcv = bfc[0];

    // FC fragments hoisted (SSA regs survive the clobber)
    const v8h wfc0 = *(const v8h*)&wfcf[(0 * 64 + lane) * 8];
    const v8h wfc1 = *(const v8h*)&wfcf[(1 * 64 + lane) * 8];

#define MFMA16(A, B, C) __builtin_amdgcn_mfma_f32_16x16x32_f16((A), (B), (C), 0, 0, 0)
#define AFRAG(pl, mt) (*(const v8h*)&wf[(((pl) * 16 + (mt)) * 64 + lane) * 8])

    // ---- z B-fragments, then one-time z-projection into registers ----
    v4f zproj[2][4][4];                  // [group][a][ty] -- 128 regs (acc side)
    {
        v8h zfrag[2];
#pragma unroll
        for (int n = 0; n < 2; ++n) {
            zfrag[n] = vzero8();
            if (q < 2) {
                const float* zp = z + (size_t)(row0 + 16 * n + c) * LAT + q * 8;
                const float4 za = *(const float4*)(zp);
                const float4 zb = *(const float4*)(zp + 4);
                zfrag[n][0] = (_Float16)za.x; zfrag[n][1] = (_Float16)za.y;
                zfrag[n][2] = (_Float16)za.z; zfrag[n][3] = (_Float16)za.w;
                zfrag[n][4] = (_Float16)zb.x; zfrag[n][5] = (_Float16)zb.y;
                zfrag[n][6] = (_Float16)zb.z; zfrag[n][7] = (_Float16)zb.w;
            }
            if (q == 2) zfrag[n][0] = (_Float16)1.0f;   // bias slot
        }
#pragma unroll
        for (int a = 0; a < 4; ++a)
#pragma unroll
            for (int ty = 0; ty < 4; ++ty) {
                const int mt = 4 * ty + a;
                const v8h zwf = *(const v8h*)&zw[((size_t)mt * 64 + lane) * 8];
                const v4f zz = {0.f, 0.f, 0.f, 0.f};
                zproj[0][a][ty] = MFMA16(zwf, zfrag[0], zz);
                zproj[1][a][ty] = MFMA16(zwf, zfrag[1], zz);
            }
    }
    __syncthreads();   // all waves done with the zw overlay before h-state use

    v8h hf[2][2], gf[2][2];              // [group][k-half] B-frags
    v2f c0s[2][8], c1s[2][8];            // c-state as r-pairs
#pragma unroll
    for (int n = 0; n < 2; ++n) {
        hf[n][0] = vzero8(); hf[n][1] = vzero8();
        gf[n][0] = vzero8(); gf[n][1] = vzero8();
#pragma unroll
        for (int i = 0; i < 8; ++i) { c0s[n][i] = (v2f){0.f, 0.f}; c1s[n][i] = (v2f){0.f, 0.f}; }
    }

    auto l0_part = [&]() {   // L0: acc init = zproj, planes 0,1; writes h0
#pragma unroll
        for (int a = 0; a < 4; ++a) {
            v4f acc[2][4];
#pragma unroll
            for (int ty = 0; ty < 4; ++ty) {
                const int mt = 4 * ty + a;
                const v8h a0 = AFRAG(0, mt);
                const v8h a1 = AFRAG(1, mt);
                v4f t0 = MFMA16(a0, hf[0][0], zproj[0][a][ty]);
                v4f t1 = MFMA16(a0, hf[1][0], zproj[1][a][ty]);
                t0 = MFMA16(a1, hf[0][1], t0);
                t1 = MFMA16(a1, hf[1][1], t1);
                acc[0][ty] = t0;  acc[1][ty] = t1;
            }
#pragma unroll
            for (int n = 0; n < 2; ++n) {
                const v2f h01 = cell_update2(
                    (v2f){acc[n][0][0], acc[n][0][1]}, (v2f){acc[n][1][0], acc[n][1][1]},
                    (v2f){acc[n][2][0], acc[n][2][1]}, (v2f){acc[n][3][0], acc[n][3][1]},
                    c0s[n][a * 2]);
                const v2f h23 = cell_update2(
                    (v2f){acc[n][0][2], acc[n][0][3]}, (v2f){acc[n][1][2], acc[n][1][3]},
                    (v2f){acc[n][2][2], acc[n][2][3]}, (v2f){acc[n][3][2], acc[n][3][3]},
                    c0s[n][a * 2 + 1]);
                *(v4h*)&stW[(c + 16 * n) * 72 + 16 * a + 4 * q] =
                    pack4(h01.x, h01.y, h23.x, h23.y);
            }
        }
    };

    auto l0_finish = [&]() {
#pragma unroll
        for (int n = 0; n < 2; ++n) {
            hf[n][0] = *(const v8h*)&stW[(c + 16 * n) * 72 + 8 * q];
            hf[n][1] = *(const v8h*)&stW[(c + 16 * n) * 72 + 32 + 8 * q];
        }
    };

    auto l1_part = [&]() {   // L1: planes 2,3 on hf; 4,5 on gf; writes h1
#pragma unroll
        for (int a = 0; a < 4; ++a) {
            v4f acc[2][4];
#pragma unroll
            for (int ty = 0; ty < 4; ++ty) {
                const int mt = 4 * ty + a;
                const v4f b  = *(const v4f*)&bsum1[64 * ty + 16 * a + 4 * q];
                const v8h a2 = AFRAG(2, mt);
                const v8h a3 = AFRAG(3, mt);
                const v8h a4 = AFRAG(4, mt);
                const v8h a5 = AFRAG(5, mt);
                v4f t0 = MFMA16(a2, hf[0][0], b);
                v4f t1 = MFMA16(a2, hf[1][0], b);
                t0 = MFMA16(a3, hf[0][1], t0);  t1 = MFMA16(a3, hf[1][1], t1);
                t0 = MFMA16(a4, gf[0][0], t0);  t1 = MFMA16(a4, gf[1][0], t1);
                t0 = MFMA16(a5, gf[0][1], t0);  t1 = MFMA16(a5, gf[1][1], t1);
                acc[0][ty] = t0;  acc[1][ty] = t1;
            }
#pragma unroll
            for (int n = 0; n < 2; ++n) {
                const v2f h01 = cell_update2(
                    (v2f){acc[n][0][0], acc[n][0][1]}, (v2f){acc[n][1][0], acc[n][1][1]},
                    (v2f){acc[n][2][0], acc[n][2][1]}, (v2f){acc[n][3][0], acc[n][3][1]},
                    c1s[n][a * 2]);
                const v2f h23 = cell_update2(
                    (v2f){acc[n][0][2], acc[n][0][3]}, (v2f){acc[n][1][2], acc[n][1][3]},
                    (v2f){acc[n][2][2], acc[n][2][3]}, (v2f){acc[n][3][2], acc[n][3][3]},
                    c1s[n][a * 2 + 1]);
                *(v4h*)&stW[(c + 16 * n) * 72 + 16 * a + 4 * q] =
                    pack4(h01.x, h01.y, h23.x, h23.y);
            }
        }
    };

    auto l1_finish = [&](int trow) {   // gf <- h1, FC MFMA, out
#pragma unroll
        for (int n = 0; n < 2; ++n) {
            gf[n][0] = *(const v8h*)&stW[(c + 16 * n) * 72 + 8 * q];
            gf[n][1] = *(const v8h*)&stW[(c + 16 * n) * 72 + 32 + 8 * q];
        }
#pragma unroll
        for (int n = 0; n < 2; ++n) {
            v4f f = {0.f, 0.f, 0.f, 0.f};
            f = MFMA16(wfc0, gf[n][0], f);
            f = MFMA16(wfc1, gf[n][1], f);
            if (lane < 16)
                out[(size_t)(row0 + 16 * n + lane) * TSTEPS + trow] = f[0] + bfcv;
        }
    };

    /* --------------------------- pipeline --------------------------- */
    l0_part();          // h0(0)  (hf, gf zero)
    l0_finish();

#pragma unroll 1
    for (int tt = 1; tt < TSTEPS; ++tt) {
        // Kill LICM (see header comment). Emits no instructions.
        __asm__ __volatile__("" ::: "memory");
        l1_part();           // L1(tt-1): uses hf=h0(tt-1), gf=h1(tt-2); writes h1
        l1_finish(tt - 1);   // gf <- h1(tt-1), FC, out
        l0_part();           // L0(tt): uses zproj + hf; writes h0(tt)
        l0_finish();         // hf <- h0(tt)
    }

    __asm__ __volatile__("" ::: "memory");
    l1_part();          // L1(14)
    l1_finish(TSTEPS - 1);

#undef AFRAG
#undef MFMA16
}

extern "C" void kernel_launch(void* const* d_in, const int* in_sizes, int n_in,
                              void* d_out, int out_size, void* d_ws, size_t ws_size,
                              hipStream_t stream)
{
    (void)in_sizes; (void)n_in; (void)out_size; (void)d_ws; (void)ws_size;

    const float* z    = (const float*)d_in[0];
    const float* Wih0 = (const float*)d_in[1];
    const float* Whh0 = (const float*)d_in[2];
    const float* bih0 = (const float*)d_in[3];
    const float* bhh0 = (const float*)d_in[4];
    const float* Wih1 = (const float*)d_in[5];
    const float* Whh1 = (const float*)d_in[6];
    const float* bih1 = (const float*)d_in[7];
    const float* bhh1 = (const float*)d_in[8];
    const float* Wfc  = (const float*)d_in[9];
    const float* bfc  = (const float*)d_in[10];

    lstm2_zp<<<dim3(NBATCH / 256), dim3(512), 0, stream>>>(
        z, Wih0, Whh0, bih0, bhh0, Wih1, Whh1, bih1, bhh1, Wfc, bfc,
        (float*)d_out);
}

// Round 16
// 253.084 us; speedup vs baseline: 1.0289x; 1.0067x over previous
//
#include <hip/hip_runtime.h>

#define TSTEPS 15
#define HID    64
#define LAT    16
#define NBATCH 65536
#define LOG2E  1.44269504088896f

typedef _Float16 v8h __attribute__((ext_vector_type(8)));
typedef _Float16 v4h __attribute__((ext_vector_type(4)));
typedef _Float16 v2h __attribute__((ext_vector_type(2)));
typedef float    v4f __attribute__((ext_vector_type(4)));

__device__ __forceinline__ v8h vzero8() {
    v8h v;
#pragma unroll
    for (int i = 0; i < 8; ++i) v[i] = (_Float16)0.0f;
    return v;
}

// v_cvt_pkrtz returns __fp16x2; bit-cast to our _Float16x2 (same bits).
__device__ __forceinline__ v4h pack4(float a, float b, float c, float d) {
    const v2h lo = __builtin_bit_cast(v2h, __builtin_amdgcn_cvt_pkrtz(a, b));
    const v2h hi = __builtin_bit_cast(v2h, __builtin_amdgcn_cvt_pkrtz(c, d));
    return __builtin_shufflevector(lo, hi, 0, 1, 2, 3);
}

// LSTM cell update with shared-rcp activations. Gate pre-acts ai/af/ag/ao
// arrive PRE-SCALED by log2e (folded into staged weights/biases), so
// exp2(-x) needs no multiply (neg is a free src modifier).
//   sig(a)*tanh(b) = (1-e2)*rcp((1+e1)(1+e2)),  e1=exp2(-a'), e2=exp2(-2b')
// 5 exp2 + 3 rcp per unit (was 5 exp + 5 rcp + pre-multiplies).
__device__ __forceinline__ float cell_update(float ai, float af, float ag,
                                             float ao, float& cst) {
    const float ei = __builtin_amdgcn_exp2f(-ai);
    const float ef = __builtin_amdgcn_exp2f(-af);
    const float eg = __builtin_amdgcn_exp2f(-2.0f * ag);
    const float eo = __builtin_amdgcn_exp2f(-ao);
    const float ig = (1.0f - eg) *
        __builtin_amdgcn_rcpf((1.0f + ei) * (1.0f + eg));      // i*g
    const float f  = __builtin_amdgcn_rcpf(1.0f + ef);          // forget gate
    const float cc = fmaf(f, cst, ig);
    cst = cc;
    const float ec = __builtin_amdgcn_exp2f(cc * (-2.0f * LOG2E));  // true scale
    return (1.0f - ec) *
        __builtin_amdgcn_rcpf((1.0f + eo) * (1.0f + ec));      // o*tanh(c)
}

// Software-pipelined fused 2-layer LSTM + FC. == round-13 champion (208 us)
// with one refinement: body order l1->l1_finish->l0->l0_finish removes the
// h1pk deferral registers (r15 analysis, unconfounded here).
//
// 16 waves/block (1024 thr) x N=16 batch/wave -> 4 waves/SIMD (the cap:
// 112 KB weight residency forces 1 block/CU). At this occupancy the
// 128-reg unified budget splits 64 VGPR + 64 AGPR; VGPR_Count=64 is
// benign here (NOT the r3/r4 spill storm; tripwire is WRITE_SIZE ~5.9 MB
// / FETCH ~3.5 MB).
//
// LOAD-BEARING (round 7): without the per-iteration asm memory clobber,
// LICM hoists all A-fragment ds_reads (448 VGPRs worth) out of the t-loop
// -> forced scratch spill -> 3-4 GB HBM scratch traffic. DO NOT REMOVE.
// (Pre-loop register values -- wfc fragments, zfrag -- are SSA and
// survive the clobber.)
//
// Plateau record (rounds 13-15): ILP dual-stream merge, cohort phase-split,
// and N=32+zproj LDS-traffic halving all landed 208-215 us. The wall is
// latency-structural: per-step recurrence chain (MFMA -> trans epilogue ->
// LDS C->B round trip) with occupancy hard-capped at 4 waves/SIMD by
// weight residency. VALU-issue floor ~120-130 us; trans floor ~51 us.
//
//   D[m=gate(256), n=batch(16)] = A[weights*log2e] * B[z | h0 | x | h1]
// wf planes: 0=Wih0(z,K16; k=16 -> bias; rest 0) 1,2=Whh0 3,4=Wih1 5,6=Whh1.
// Gate order (PyTorch): 0=i,1=f,2=g,3=o ; g = 64*type + u, u=16a+4q+r;
// acc[ty] -> ty IS the gate type (mt = 4*ty+a).
__global__ __launch_bounds__(1024)
__attribute__((amdgpu_waves_per_eu(4, 4)))
void lstm2_final(
        const float* __restrict__ z,
        const float* __restrict__ Wih0, const float* __restrict__ Whh0,
        const float* __restrict__ bih0, const float* __restrict__ bhh0,
        const float* __restrict__ Wih1, const float* __restrict__ Whh1,
        const float* __restrict__ bih1, const float* __restrict__ bhh1,
        const float* __restrict__ Wfc,  const float* __restrict__ bfc,
        float* __restrict__ out)
{
    __shared__ __align__(16) _Float16 wf[7 * 16 * 64 * 8];   // 114688 B
    __shared__ __align__(16) _Float16 wfcf[2 * 64 * 8];      //   2048 B
    __shared__ __align__(16) float    bsum1[256];            //   1024 B
    __shared__ __align__(16) _Float16 state[16][16 * 72];    //  36864 B
                                                             // 154624 B total

    const int tid  = threadIdx.x;
    const int wave = tid >> 6;           // 0..15
    const int lane = tid & 63;
    const int q    = lane >> 4;          // quad
    const int c    = lane & 15;          // batch col
    const int row0 = blockIdx.x * 256 + wave * 16;   // wave's batch base

    /* ------- one-time staging: weights + biases, all scaled by log2e ----- */
#pragma unroll 2
    for (int e = tid; e < 7 * 16 * 64 * 8; e += 1024) {
        const int j  = e & 7;
        const int lm = (e >> 3) & 63;
        const int mt = (e >> 9) & 15;
        const int p  = e >> 13;                  // fragment plane 0..6
        const int g  = mt * 16 + (lm & 15);      // gate row 0..255
        const int kk = (lm >> 4) * 8 + j;        // k within 32-chunk
        float v;
        if (p == 0)      v = (kk < LAT) ? Wih0[g * LAT + kk]
                           : (kk == LAT ? bih0[g] + bhh0[g] : 0.0f);
        else if (p == 1) v = Whh0[g * HID + kk];
        else if (p == 2) v = Whh0[g * HID + 32 + kk];
        else if (p == 3) v = Wih1[g * HID + kk];
        else if (p == 4) v = Wih1[g * HID + 32 + kk];
        else if (p == 5) v = Whh1[g * HID + kk];
        else             v = Whh1[g * HID + 32 + kk];
        wf[e] = (_Float16)(v * LOG2E);
    }
    // FC A-fragments: row m=0 carries Wfc (TRUE scale), rows 1..15 zero
    if (tid < 2 * 64 * 8) {
        const int e  = tid;
        const int j  = e & 7;
        const int lm = (e >> 3) & 63;
        const int kc = e >> 9;
        const int kk = kc * 32 + (lm >> 4) * 8 + j;
        wfcf[e] = ((lm & 15) == 0) ? (_Float16)Wfc[kk] : (_Float16)0.0f;
    }
    if (tid < 256) bsum1[tid] = (bih1[tid] + bhh1[tid]) * LOG2E;
    __syncthreads();   // the only barrier in the kernel

    _Float16* stW = &state[wave][0];
    const float bfcv = bfc[0];

    // FC fragments hoisted (SSA regs survive the clobber)
    const v8h wfc0 = *(const v8h*)&wfcf[(0 * 64 + lane) * 8];
    const v8h wfc1 = *(const v8h*)&wfcf[(1 * 64 + lane) * 8];

    // z B-fragment (constant over t); element k=16 = 1.0 multiplies the
    // (log2e-scaled) bias column staged in plane 0.
    v8h zfrag = vzero8();
    if (q < 2) {
        const float* zp = z + (size_t)(row0 + c) * LAT + q * 8;
        const float4 za = *(const float4*)(zp);
        const float4 zb = *(const float4*)(zp + 4);
        zfrag[0] = (_Float16)za.x; zfrag[1] = (_Float16)za.y;
        zfrag[2] = (_Float16)za.z; zfrag[3] = (_Float16)za.w;
        zfrag[4] = (_Float16)zb.x; zfrag[5] = (_Float16)zb.y;
        zfrag[6] = (_Float16)zb.z; zfrag[7] = (_Float16)zb.w;
    }
    if (q == 2) zfrag[0] = (_Float16)1.0f;   // bias slot

    v8h hf0 = vzero8(), hf1 = vzero8();   // h0/x B-frags (k-halves)
    v8h gf0 = vzero8(), gf1 = vzero8();   // h1 B-frags
    float c0s[16], c1s[16];
#pragma unroll
    for (int i = 0; i < 16; ++i) { c0s[i] = 0.0f; c1s[i] = 0.0f; }

#define AFRAG(pl, mt) (*(const v8h*)&wf[(((pl) * 16 + (mt)) * 64 + lane) * 8])
#define MFMA16(A, B, C) __builtin_amdgcn_mfma_f32_16x16x32_f16((A), (B), (C), 0, 0, 0)

    auto l0_part = [&]() {   // L0 MFMAs + epilogue + h0 stores (uses old hf)
#pragma unroll
        for (int a = 0; a < 4; ++a) {
            v4f acc0[4];
#pragma unroll
            for (int ty = 0; ty < 4; ++ty) {
                const int mt = 4 * ty + a;
                v4f t0 = {0.f, 0.f, 0.f, 0.f};
                t0 = MFMA16(AFRAG(0, mt), zfrag, t0);
                t0 = MFMA16(AFRAG(1, mt), hf0,   t0);
                t0 = MFMA16(AFRAG(2, mt), hf1,   t0);
                acc0[ty] = t0;
            }
            float hh[4];
#pragma unroll
            for (int r = 0; r < 4; ++r)
                hh[r] = cell_update(acc0[0][r], acc0[1][r], acc0[2][r],
                                    acc0[3][r], c0s[a * 4 + r]);
            *(v4h*)&stW[c * 72 + 16 * a + 4 * q] = pack4(hh[0], hh[1], hh[2], hh[3]);
        }
    };

    auto l0_finish = [&]() {   // pull new h0 into B-frag registers
        hf0 = *(const v8h*)&stW[c * 72 + 8 * q];
        hf1 = *(const v8h*)&stW[c * 72 + 32 + 8 * q];
    };

    auto l1_part = [&]() {   // L1 MFMAs + epilogue + h1 stores (old hf, gf)
#pragma unroll
        for (int a = 0; a < 4; ++a) {
            v4f acc1[4];
#pragma unroll
            for (int ty = 0; ty < 4; ++ty) {
                const int mt = 4 * ty + a;
                v4f t0 = *(const v4f*)&bsum1[64 * ty + 16 * a + 4 * q];
                t0 = MFMA16(AFRAG(3, mt), hf0, t0);
                t0 = MFMA16(AFRAG(4, mt), hf1, t0);
                t0 = MFMA16(AFRAG(5, mt), gf0, t0);
                t0 = MFMA16(AFRAG(6, mt), gf1, t0);
                acc1[ty] = t0;
            }
            float hh[4];
#pragma unroll
            for (int r = 0; r < 4; ++r)
                hh[r] = cell_update(acc1[0][r], acc1[1][r], acc1[2][r],
                                    acc1[3][r], c1s[a * 4 + r]);
            *(v4h*)&stW[c * 72 + 16 * a + 4 * q] = pack4(hh[0], hh[1], hh[2], hh[3]);
        }
    };

    auto l1_finish = [&](int trow) {   // gf <- h1, FC MFMA, out
        gf0 = *(const v8h*)&stW[c * 72 + 8 * q];
        gf1 = *(const v8h*)&stW[c * 72 + 32 + 8 * q];
        v4f f = {0.f, 0.f, 0.f, 0.f};
        f = MFMA16(wfc0, gf0, f);
        f = MFMA16(wfc1, gf1, f);
        if (lane < 16)
            out[(size_t)(row0 + lane) * TSTEPS + trow] = f[0] + bfcv;
    };

    /* --------------------------- pipeline --------------------------- */
    l0_part();          // L0 step 0 (hf, gf are zero)
    l0_finish();

#pragma unroll 1
    for (int tt = 1; tt < TSTEPS; ++tt) {
        // Kill LICM (see header comment). Emits no instructions.
        __asm__ __volatile__("" ::: "memory");
        // L1(tt-1) first: uses hf=h0(tt-1), gf=h1(tt-2); writes h1 to stW.
        // Then L0(tt): depends only on hf (unchanged until l0_finish).
        // stW content is dead at each overwrite (read into regs just after).
        l1_part();
        l1_finish(tt - 1);   // gf <- h1(tt-1), FC, out row tt-1
        l0_part();           // writes h0(tt)
        l0_finish();         // hf <- h0(tt)
    }

    __asm__ __volatile__("" ::: "memory");
    l1_part();          // L1 step 14
    l1_finish(TSTEPS - 1);

#undef AFRAG
#undef MFMA16
}

extern "C" void kernel_launch(void* const* d_in, const int* in_sizes, int n_in,
                              void* d_out, int out_size, void* d_ws, size_t ws_size,
                              hipStream_t stream)
{
    (void)in_sizes; (void)n_in; (void)out_size; (void)d_ws; (void)ws_size;

    const float* z    = (const float*)d_in[0];
    const float* Wih0 = (const float*)d_in[1];
    const float* Whh0 = (const float*)d_in[2];
    const float* bih0 = (const float*)d_in[3];
    const float* bhh0 = (const float*)d_in[4];
    const float* Wih1 = (const float*)d_in[5];
    const float* Whh1 = (const float*)d_in[6];
    const float* bih1 = (const float*)d_in[7];
    const float* bhh1 = (const float*)d_in[8];
    const float* Wfc  = (const float*)d_in[9];
    const float* bfc  = (const float*)d_in[10];

    lstm2_final<<<dim3(NBATCH / 256), dim3(1024), 0, stream>>>(
        z, Wih0, Whh0, bih0, bhh0, Wih1, Whh1, bih1, bhh1, Wfc, bfc,
        (float*)d_out);
}